// Round 1
// baseline (271.260 us; speedup 1.0000x reference)
//
#include <hip/hip_runtime.h>

#define D 128

// ---------------------------------------------------------------------------
// Kernel 1: build CSR row_ptr from sorted COO row array.
// row_ptr[n] = first edge index e with row[e] >= n; row_ptr[N] = E.
// ---------------------------------------------------------------------------
__global__ void build_rowptr_kernel(const int* __restrict__ row,
                                    int* __restrict__ row_ptr,
                                    int n_nodes, int n_edges) {
    int e = blockIdx.x * blockDim.x + threadIdx.x;
    if (e >= n_edges) return;
    int r = row[e];
    int rp = (e == 0) ? -1 : row[e - 1];
    // this edge is the first edge for nodes (rp, r]
    for (int n = rp + 1; n <= r; ++n) row_ptr[n] = e;
    if (e == n_edges - 1) {
        for (int n = r + 1; n <= n_nodes; ++n) row_ptr[n] = n_edges;
    }
}

// ---------------------------------------------------------------------------
// Kernel 2: SpMM (gather-scale-segment-sum). One 128-thread block per node.
// Thread d owns feature dim d. Writes out_l into d_out (later read in-place
// by the fused GEMM).
// ---------------------------------------------------------------------------
__global__ __launch_bounds__(128) void spmm_kernel(
    const float* __restrict__ x,
    const int* __restrict__ row_ptr,
    const int* __restrict__ col,
    const float* __restrict__ val,
    float* __restrict__ out_l) {
    const int n = blockIdx.x;
    const int d = threadIdx.x;
    const int start = row_ptr[n];
    const int end = row_ptr[n + 1];
    float acc = 0.0f;
    for (int e = start; e < end; ++e) {
        const int c = col[e];       // uniform across block -> broadcast
        const float v = val[e];
        acc += v * x[(size_t)c * D + d];   // 512B contiguous gather per edge
    }
    out_l[(size_t)n * D + d] = acc;
}

// ---------------------------------------------------------------------------
// Kernel 3: fused in-place GEMM: out = out_l @ W_l + b_l + x @ W_r
// Virtual A = [out_l | x]  (M x 256), virtual W = [W_l ; W_r]  (256 x 128).
// Tile: 64 rows x 128 cols per 256-thread block; K staged in 4 chunks of 64.
// Thread (tx,ty): tx=tid&15 owns cols {tx*4..+4} u {64+tx*4..+4},
//                 ty=tid>>4 owns rows {ty*4..+4}.  acc[4][8].
// In-place safe: block reads only its own 64 rows of `out` (kt=0,1), all
// before the epilogue write.
// ---------------------------------------------------------------------------
__global__ __launch_bounds__(256) void fused_gemm_kernel(
    const float* __restrict__ xin,
    const float* __restrict__ W_l,
    const float* __restrict__ b_l,
    const float* __restrict__ W_r,
    float* __restrict__ out,   // holds out_l on entry, final result on exit
    int M) {
    __shared__ float As[64][68];    // [m][k]   pad 68: float4-aligned, 2-way max
    __shared__ float Ws[64][132];   // [k][j]   pad 132: float4-aligned, 2-way max
    const int tid = threadIdx.x;
    const int tx = tid & 15;
    const int ty = tid >> 4;
    const int ty4 = ty * 4;
    const int m0 = blockIdx.x * 64;

    float acc[4][8];
#pragma unroll
    for (int i = 0; i < 4; ++i)
#pragma unroll
        for (int j = 0; j < 8; ++j) acc[i][j] = 0.0f;

    for (int kt = 0; kt < 4; ++kt) {
        const float* Asrc = (kt < 2) ? out : xin;
        const float* Wsrc = (kt < 2) ? W_l : W_r;
        const int koff = (kt & 1) * 64;

        __syncthreads();   // previous chunk's LDS reads complete before overwrite
        // stage A chunk: 64 rows x 64 k  (4 float4 per thread)
#pragma unroll
        for (int r = 0; r < 4; ++r) {
            const int idx = tid + r * 256;     // 0..1023 float4 slots
            const int m = idx >> 4;            // 0..63
            const int kq = idx & 15;           // 0..15  (float4 within row)
            float4 a = make_float4(0.f, 0.f, 0.f, 0.f);
            if (m0 + m < M)
                a = *(const float4*)&Asrc[(size_t)(m0 + m) * D + koff + kq * 4];
            *(float4*)&As[m][kq * 4] = a;
        }
        // stage W chunk: 64 k-rows x 128 cols (8 float4 per thread)
#pragma unroll
        for (int r = 0; r < 8; ++r) {
            const int idx = tid + r * 256;     // 0..2047 float4 slots
            const int k = idx >> 5;            // 0..63
            const int j4 = idx & 31;           // 0..31
            *(float4*)&Ws[k][j4 * 4] =
                *(const float4*)&Wsrc[(size_t)(koff + k) * D + j4 * 4];
        }
        __syncthreads();

#pragma unroll 4
        for (int k = 0; k < 64; ++k) {
            const float a0 = As[ty4 + 0][k];
            const float a1 = As[ty4 + 1][k];
            const float a2 = As[ty4 + 2][k];
            const float a3 = As[ty4 + 3][k];
            const float4 w0 = *(const float4*)&Ws[k][tx * 4];
            const float4 w1 = *(const float4*)&Ws[k][64 + tx * 4];
            acc[0][0] += a0 * w0.x; acc[0][1] += a0 * w0.y;
            acc[0][2] += a0 * w0.z; acc[0][3] += a0 * w0.w;
            acc[0][4] += a0 * w1.x; acc[0][5] += a0 * w1.y;
            acc[0][6] += a0 * w1.z; acc[0][7] += a0 * w1.w;
            acc[1][0] += a1 * w0.x; acc[1][1] += a1 * w0.y;
            acc[1][2] += a1 * w0.z; acc[1][3] += a1 * w0.w;
            acc[1][4] += a1 * w1.x; acc[1][5] += a1 * w1.y;
            acc[1][6] += a1 * w1.z; acc[1][7] += a1 * w1.w;
            acc[2][0] += a2 * w0.x; acc[2][1] += a2 * w0.y;
            acc[2][2] += a2 * w0.z; acc[2][3] += a2 * w0.w;
            acc[2][4] += a2 * w1.x; acc[2][5] += a2 * w1.y;
            acc[2][6] += a2 * w1.z; acc[2][7] += a2 * w1.w;
            acc[3][0] += a3 * w0.x; acc[3][1] += a3 * w0.y;
            acc[3][2] += a3 * w0.z; acc[3][3] += a3 * w0.w;
            acc[3][4] += a3 * w1.x; acc[3][5] += a3 * w1.y;
            acc[3][6] += a3 * w1.z; acc[3][7] += a3 * w1.w;
        }
    }

    // epilogue: add bias, write back (cols tx*4 and 64+tx*4)
    const float4 bv0 = *(const float4*)&b_l[tx * 4];
    const float4 bv1 = *(const float4*)&b_l[64 + tx * 4];
#pragma unroll
    for (int i = 0; i < 4; ++i) {
        const int m = m0 + ty4 + i;
        if (m < M) {
            float4 o0, o1;
            o0.x = acc[i][0] + bv0.x; o0.y = acc[i][1] + bv0.y;
            o0.z = acc[i][2] + bv0.z; o0.w = acc[i][3] + bv0.w;
            o1.x = acc[i][4] + bv1.x; o1.y = acc[i][5] + bv1.y;
            o1.z = acc[i][6] + bv1.z; o1.w = acc[i][7] + bv1.w;
            *(float4*)&out[(size_t)m * D + tx * 4] = o0;
            *(float4*)&out[(size_t)m * D + 64 + tx * 4] = o1;
        }
    }
}

extern "C" void kernel_launch(void* const* d_in, const int* in_sizes, int n_in,
                              void* d_out, int out_size, void* d_ws, size_t ws_size,
                              hipStream_t stream) {
    const float* x   = (const float*)d_in[0];
    const int*   row = (const int*)d_in[1];
    const int*   col = (const int*)d_in[2];
    const float* val = (const float*)d_in[3];
    const float* W_l = (const float*)d_in[4];
    const float* b_l = (const float*)d_in[5];
    const float* W_r = (const float*)d_in[6];
    float* out = (float*)d_out;

    const int n_nodes = in_sizes[0] / D;
    const int n_edges = in_sizes[1];

    int* row_ptr = (int*)d_ws;   // (n_nodes+1) ints

    build_rowptr_kernel<<<(n_edges + 255) / 256, 256, 0, stream>>>(
        row, row_ptr, n_nodes, n_edges);
    spmm_kernel<<<n_nodes, 128, 0, stream>>>(x, row_ptr, col, val, out);
    fused_gemm_kernel<<<(n_nodes + 63) / 64, 256, 0, stream>>>(
        x, W_l, b_l, W_r, out, n_nodes);
}

// Round 2
// 132.515 us; speedup vs baseline: 2.0470x; 2.0470x over previous
//
#include <hip/hip_runtime.h>

#define D 128
typedef unsigned int uint32;
typedef unsigned short ushort16;
typedef __bf16 bf16x8 __attribute__((ext_vector_type(8)));
typedef float f32x4 __attribute__((ext_vector_type(4)));

__device__ __forceinline__ unsigned short f2bf(float f) {
    unsigned u = __float_as_uint(f);
    unsigned r = u + 0x7FFFu + ((u >> 16) & 1u);   // round-to-nearest-even
    return (unsigned short)(r >> 16);
}
__device__ __forceinline__ float bflo(uint32 u) { return __uint_as_float(u << 16); }
__device__ __forceinline__ float bfhi(uint32 u) { return __uint_as_float(u & 0xFFFF0000u); }

// ---------------------------------------------------------------------------
// CSR row_ptr from sorted COO rows.
// ---------------------------------------------------------------------------
__global__ void build_rowptr_kernel(const int* __restrict__ row,
                                    int* __restrict__ row_ptr,
                                    int n_nodes, int n_edges) {
    int e = blockIdx.x * blockDim.x + threadIdx.x;
    if (e >= n_edges) return;
    int r = row[e];
    int rp = (e == 0) ? -1 : row[e - 1];
    for (int n = rp + 1; n <= r; ++n) row_ptr[n] = e;
    if (e == n_edges - 1) {
        for (int n = r + 1; n <= n_nodes; ++n) row_ptr[n] = n_edges;
    }
}

// ---------------------------------------------------------------------------
// x (f32) -> xh (bf16), 8 elems/thread.
// ---------------------------------------------------------------------------
__global__ __launch_bounds__(256) void convert_x_kernel(
    const float* __restrict__ x, unsigned short* __restrict__ xh, int n8) {
    int id = blockIdx.x * blockDim.x + threadIdx.x;
    if (id >= n8) return;
    const float4* p = (const float4*)x + (size_t)id * 2;
    float4 a = p[0], b = p[1];
    uint4 o;
    o.x = f2bf(a.x) | ((uint32)f2bf(a.y) << 16);
    o.y = f2bf(a.z) | ((uint32)f2bf(a.w) << 16);
    o.z = f2bf(b.x) | ((uint32)f2bf(b.y) << 16);
    o.w = f2bf(b.z) | ((uint32)f2bf(b.w) << 16);
    ((uint4*)xh)[id] = o;
}

// ---------------------------------------------------------------------------
// W_l, W_r (f32 [k][n]) -> Wlt, Wrt (bf16 [n][k])  (transpose for B-fragments)
// ---------------------------------------------------------------------------
__global__ __launch_bounds__(256) void convert_w_kernel(
    const float* __restrict__ Wl, const float* __restrict__ Wr,
    unsigned short* __restrict__ Wlt, unsigned short* __restrict__ Wrt) {
    int id = blockIdx.x * blockDim.x + threadIdx.x;   // 0..16383
    if (id >= 16384) return;
    int n = id & 127, k = id >> 7;
    Wlt[n * 128 + k] = f2bf(Wl[k * 128 + n]);
    Wrt[n * 128 + k] = f2bf(Wr[k * 128 + n]);
}

// ---------------------------------------------------------------------------
// SpMM, bf16 gather. One wave per node; 4 edge-groups x 16 lanes; each lane
// loads 16B (8 bf16) of the gathered row -> 4 gathers in flight per wave.
// Cross-group reduce via shfl_xor(16/32); writes bf16 out_l.
// ---------------------------------------------------------------------------
__global__ __launch_bounds__(256) void spmm_bf16_kernel(
    const unsigned short* __restrict__ xh,
    const int* __restrict__ row_ptr,
    const int* __restrict__ col,
    const float* __restrict__ val,
    unsigned short* __restrict__ outlh, int n_nodes) {
    const int wid = threadIdx.x >> 6;
    const int n = blockIdx.x * 4 + wid;
    if (n >= n_nodes) return;
    const int lane = threadIdx.x & 63;
    const int g = lane >> 4;      // edge slot 0..3
    const int q = lane & 15;      // 16B chunk (8 dims)

    const int start = row_ptr[n];
    const int end = row_ptr[n + 1];

    float acc[8] = {0.f, 0.f, 0.f, 0.f, 0.f, 0.f, 0.f, 0.f};

    int i = start + g;
    int c = 0; float v = 0.f;
    if (i < end) { c = col[i]; v = val[i]; }
    while (i < end) {
        const int i2 = i + 4;
        int c2 = 0; float v2 = 0.f;
        if (i2 < end) { c2 = col[i2]; v2 = val[i2]; }   // prefetch next edge
        const uint4 raw = *(const uint4*)&xh[(size_t)c * D + q * 8];
        acc[0] += v * bflo(raw.x); acc[1] += v * bfhi(raw.x);
        acc[2] += v * bflo(raw.y); acc[3] += v * bfhi(raw.y);
        acc[4] += v * bflo(raw.z); acc[5] += v * bfhi(raw.z);
        acc[6] += v * bflo(raw.w); acc[7] += v * bfhi(raw.w);
        i = i2; c = c2; v = v2;
    }
#pragma unroll
    for (int j = 0; j < 8; ++j) {
        acc[j] += __shfl_xor(acc[j], 16, 64);
        acc[j] += __shfl_xor(acc[j], 32, 64);
    }
    if (g == 0) {
        uint4 o;
        o.x = f2bf(acc[0]) | ((uint32)f2bf(acc[1]) << 16);
        o.y = f2bf(acc[2]) | ((uint32)f2bf(acc[3]) << 16);
        o.z = f2bf(acc[4]) | ((uint32)f2bf(acc[5]) << 16);
        o.w = f2bf(acc[6]) | ((uint32)f2bf(acc[7]) << 16);
        *(uint4*)&outlh[(size_t)n * D + q * 8] = o;
    }
}

// ---------------------------------------------------------------------------
// MFMA GEMM: out = [out_l_h | xh] @ [Wlt;Wrt]^T + b_l   (K=256, bf16 in, f32 out)
// Block: 64 rows x 128 cols, 4 waves (2x2), wave tile 32x64.
// A/B fragments loaded directly from global (16B contiguous per lane).
// ---------------------------------------------------------------------------
__global__ __launch_bounds__(256) void gemm_mfma_kernel(
    const unsigned short* __restrict__ xh,
    const unsigned short* __restrict__ outlh,
    const unsigned short* __restrict__ Wlt,
    const unsigned short* __restrict__ Wrt,
    const float* __restrict__ b_l,
    float* __restrict__ out, int M) {
    const int tid = threadIdx.x;
    const int wid = tid >> 6, lane = tid & 63;
    const int wm = wid >> 1, wn = wid & 1;
    const int m0 = blockIdx.x * 64 + wm * 32;
    const int n0 = wn * 64;
    const int fr = lane & 15;          // A-row / B-col / C-col within frag
    const int kofs = (lane >> 4) * 8;  // k offset within K-step

    f32x4 acc[2][4];
#pragma unroll
    for (int mr = 0; mr < 2; ++mr)
#pragma unroll
        for (int nr = 0; nr < 4; ++nr) acc[mr][nr] = (f32x4){0.f, 0.f, 0.f, 0.f};

#pragma unroll
    for (int s = 0; s < 8; ++s) {
        const unsigned short* Abase = (s < 4) ? outlh : xh;
        const unsigned short* Wbase = (s < 4) ? Wlt : Wrt;
        const int k0 = (s & 3) * 32;
        bf16x8 a[2], b[4];
#pragma unroll
        for (int mr = 0; mr < 2; ++mr)
            a[mr] = *(const bf16x8*)&Abase[(size_t)(m0 + mr * 16 + fr) * D + k0 + kofs];
#pragma unroll
        for (int nr = 0; nr < 4; ++nr)
            b[nr] = *(const bf16x8*)&Wbase[(n0 + nr * 16 + fr) * D + k0 + kofs];
#pragma unroll
        for (int mr = 0; mr < 2; ++mr)
#pragma unroll
            for (int nr = 0; nr < 4; ++nr)
                acc[mr][nr] = __builtin_amdgcn_mfma_f32_16x16x32_bf16(
                    a[mr], b[nr], acc[mr][nr], 0, 0, 0);
    }

    const int r0 = (lane >> 4) * 4;    // C-row base within frag
#pragma unroll
    for (int nr = 0; nr < 4; ++nr) {
        const int ncol = n0 + nr * 16 + fr;
        const float bias = b_l[ncol];
#pragma unroll
        for (int mr = 0; mr < 2; ++mr) {
#pragma unroll
            for (int j = 0; j < 4; ++j) {
                const int m = m0 + mr * 16 + r0 + j;
                if (m < M) out[(size_t)m * D + ncol] = acc[mr][nr][j] + bias;
            }
        }
    }
}

// ===========================================================================
// Fallback f32 path (round-1 kernels) if ws is too small for bf16 staging.
// ===========================================================================
__global__ __launch_bounds__(128) void spmm_kernel(
    const float* __restrict__ x, const int* __restrict__ row_ptr,
    const int* __restrict__ col, const float* __restrict__ val,
    float* __restrict__ out_l) {
    const int n = blockIdx.x;
    const int d = threadIdx.x;
    const int start = row_ptr[n];
    const int end = row_ptr[n + 1];
    float acc = 0.0f;
    for (int e = start; e < end; ++e)
        acc += val[e] * x[(size_t)col[e] * D + d];
    out_l[(size_t)n * D + d] = acc;
}

__global__ __launch_bounds__(256) void fused_gemm_kernel(
    const float* __restrict__ xin, const float* __restrict__ W_l,
    const float* __restrict__ b_l, const float* __restrict__ W_r,
    float* __restrict__ out, int M) {
    __shared__ float As[64][68];
    __shared__ float Ws[64][132];
    const int tid = threadIdx.x;
    const int tx = tid & 15;
    const int ty = tid >> 4;
    const int ty4 = ty * 4;
    const int m0 = blockIdx.x * 64;
    float acc[4][8];
#pragma unroll
    for (int i = 0; i < 4; ++i)
#pragma unroll
        for (int j = 0; j < 8; ++j) acc[i][j] = 0.0f;
    for (int kt = 0; kt < 4; ++kt) {
        const float* Asrc = (kt < 2) ? out : xin;
        const float* Wsrc = (kt < 2) ? W_l : W_r;
        const int koff = (kt & 1) * 64;
        __syncthreads();
#pragma unroll
        for (int r = 0; r < 4; ++r) {
            const int idx = tid + r * 256;
            const int m = idx >> 4;
            const int kq = idx & 15;
            float4 a = make_float4(0.f, 0.f, 0.f, 0.f);
            if (m0 + m < M)
                a = *(const float4*)&Asrc[(size_t)(m0 + m) * D + koff + kq * 4];
            *(float4*)&As[m][kq * 4] = a;
        }
#pragma unroll
        for (int r = 0; r < 8; ++r) {
            const int idx = tid + r * 256;
            const int k = idx >> 5;
            const int j4 = idx & 31;
            *(float4*)&Ws[k][j4 * 4] =
                *(const float4*)&Wsrc[(size_t)(koff + k) * D + j4 * 4];
        }
        __syncthreads();
#pragma unroll 4
        for (int k = 0; k < 64; ++k) {
            const float a0 = As[ty4 + 0][k], a1 = As[ty4 + 1][k];
            const float a2 = As[ty4 + 2][k], a3 = As[ty4 + 3][k];
            const float4 w0 = *(const float4*)&Ws[k][tx * 4];
            const float4 w1 = *(const float4*)&Ws[k][64 + tx * 4];
            acc[0][0] += a0 * w0.x; acc[0][1] += a0 * w0.y; acc[0][2] += a0 * w0.z; acc[0][3] += a0 * w0.w;
            acc[0][4] += a0 * w1.x; acc[0][5] += a0 * w1.y; acc[0][6] += a0 * w1.z; acc[0][7] += a0 * w1.w;
            acc[1][0] += a1 * w0.x; acc[1][1] += a1 * w0.y; acc[1][2] += a1 * w0.z; acc[1][3] += a1 * w0.w;
            acc[1][4] += a1 * w1.x; acc[1][5] += a1 * w1.y; acc[1][6] += a1 * w1.z; acc[1][7] += a1 * w1.w;
            acc[2][0] += a2 * w0.x; acc[2][1] += a2 * w0.y; acc[2][2] += a2 * w0.z; acc[2][3] += a2 * w0.w;
            acc[2][4] += a2 * w1.x; acc[2][5] += a2 * w1.y; acc[2][6] += a2 * w1.z; acc[2][7] += a2 * w1.w;
            acc[3][0] += a3 * w0.x; acc[3][1] += a3 * w0.y; acc[3][2] += a3 * w0.z; acc[3][3] += a3 * w0.w;
            acc[3][4] += a3 * w1.x; acc[3][5] += a3 * w1.y; acc[3][6] += a3 * w1.z; acc[3][7] += a3 * w1.w;
        }
    }
    const float4 bv0 = *(const float4*)&b_l[tx * 4];
    const float4 bv1 = *(const float4*)&b_l[64 + tx * 4];
#pragma unroll
    for (int i = 0; i < 4; ++i) {
        const int m = m0 + ty4 + i;
        if (m < M) {
            float4 o0, o1;
            o0.x = acc[i][0] + bv0.x; o0.y = acc[i][1] + bv0.y;
            o0.z = acc[i][2] + bv0.z; o0.w = acc[i][3] + bv0.w;
            o1.x = acc[i][4] + bv1.x; o1.y = acc[i][5] + bv1.y;
            o1.z = acc[i][6] + bv1.z; o1.w = acc[i][7] + bv1.w;
            *(float4*)&out[(size_t)m * D + tx * 4] = o0;
            *(float4*)&out[(size_t)m * D + 64 + tx * 4] = o1;
        }
    }
}

static inline size_t align256(size_t x) { return (x + 255) & ~(size_t)255; }

extern "C" void kernel_launch(void* const* d_in, const int* in_sizes, int n_in,
                              void* d_out, int out_size, void* d_ws, size_t ws_size,
                              hipStream_t stream) {
    const float* x   = (const float*)d_in[0];
    const int*   row = (const int*)d_in[1];
    const int*   col = (const int*)d_in[2];
    const float* val = (const float*)d_in[3];
    const float* W_l = (const float*)d_in[4];
    const float* b_l = (const float*)d_in[5];
    const float* W_r = (const float*)d_in[6];
    float* out = (float*)d_out;

    const int n_nodes = in_sizes[0] / D;
    const int n_edges = in_sizes[1];

    // ws layout (bf16 path)
    const size_t xh_bytes   = (size_t)n_nodes * D * 2;
    const size_t outl_bytes = (size_t)n_nodes * D * 2;
    const size_t wt_bytes   = (size_t)D * D * 2;
    const size_t rp_bytes   = (size_t)(n_nodes + 1) * 4;
    size_t off = 0;
    const size_t xh_off   = off; off += align256(xh_bytes);
    const size_t outl_off = off; off += align256(outl_bytes);
    const size_t wlt_off  = off; off += align256(wt_bytes);
    const size_t wrt_off  = off; off += align256(wt_bytes);
    const size_t rp_off   = off; off += align256(rp_bytes);
    const size_t needed   = off + 65536;   // slack for tail overrun reads

    if (ws_size >= needed) {
        unsigned short* xh    = (unsigned short*)((char*)d_ws + xh_off);
        unsigned short* outlh = (unsigned short*)((char*)d_ws + outl_off);
        unsigned short* Wlt   = (unsigned short*)((char*)d_ws + wlt_off);
        unsigned short* Wrt   = (unsigned short*)((char*)d_ws + wrt_off);
        int* row_ptr          = (int*)((char*)d_ws + rp_off);

        build_rowptr_kernel<<<(n_edges + 255) / 256, 256, 0, stream>>>(
            row, row_ptr, n_nodes, n_edges);
        const int n8 = n_nodes * D / 8;
        convert_x_kernel<<<(n8 + 255) / 256, 256, 0, stream>>>(x, xh, n8);
        convert_w_kernel<<<64, 256, 0, stream>>>(W_l, W_r, Wlt, Wrt);
        spmm_bf16_kernel<<<(n_nodes + 3) / 4, 256, 0, stream>>>(
            xh, row_ptr, col, val, outlh, n_nodes);
        gemm_mfma_kernel<<<(n_nodes + 63) / 64, 256, 0, stream>>>(
            xh, outlh, Wlt, Wrt, b_l, out, n_nodes);
    } else {
        int* row_ptr = (int*)d_ws;
        build_rowptr_kernel<<<(n_edges + 255) / 256, 256, 0, stream>>>(
            row, row_ptr, n_nodes, n_edges);
        spmm_kernel<<<n_nodes, 128, 0, stream>>>(x, row_ptr, col, val, out);
        fused_gemm_kernel<<<(n_nodes + 63) / 64, 256, 0, stream>>>(
            x, W_l, b_l, W_r, out, n_nodes);
    }
}

// Round 3
// 125.217 us; speedup vs baseline: 2.1663x; 1.0583x over previous
//
#include <hip/hip_runtime.h>

#define D 128
typedef unsigned int uint32;
typedef __bf16 bf16x8 __attribute__((ext_vector_type(8)));
typedef float f32x4 __attribute__((ext_vector_type(4)));

__device__ __forceinline__ unsigned short f2bf(float f) {
    unsigned u = __float_as_uint(f);
    unsigned r = u + 0x7FFFu + ((u >> 16) & 1u);   // round-to-nearest-even
    return (unsigned short)(r >> 16);
}
__device__ __forceinline__ float bflo(uint32 u) { return __uint_as_float(u << 16); }
__device__ __forceinline__ float bfhi(uint32 u) { return __uint_as_float(u & 0xFFFF0000u); }

__device__ __forceinline__ void fma8(float* acc, uint4 r, float v) {
    acc[0] += v * bflo(r.x); acc[1] += v * bfhi(r.x);
    acc[2] += v * bflo(r.y); acc[3] += v * bfhi(r.y);
    acc[4] += v * bflo(r.z); acc[5] += v * bfhi(r.z);
    acc[6] += v * bflo(r.w); acc[7] += v * bfhi(r.w);
}

// ---------------------------------------------------------------------------
// Fused prep: [0, nbConv)       -> x f32 -> bf16
//             [nbConv, +nbRp)   -> CSR row_ptr from sorted rows
//             [.., +64)         -> W transpose+convert
// ---------------------------------------------------------------------------
__global__ __launch_bounds__(256) void prep_kernel(
    const float* __restrict__ x, unsigned short* __restrict__ xh, int n8,
    const int* __restrict__ row, int* __restrict__ row_ptr,
    int n_nodes, int n_edges,
    const float* __restrict__ Wl, const float* __restrict__ Wr,
    unsigned short* __restrict__ Wlt, unsigned short* __restrict__ Wrt,
    int nbConv, int nbRp) {
    const int b = blockIdx.x;
    if (b < nbConv) {
        const int id = b * 256 + threadIdx.x;
        if (id < n8) {
            const float4* p = (const float4*)x + (size_t)id * 2;
            float4 a = p[0], bb = p[1];
            uint4 o;
            o.x = f2bf(a.x) | ((uint32)f2bf(a.y) << 16);
            o.y = f2bf(a.z) | ((uint32)f2bf(a.w) << 16);
            o.z = f2bf(bb.x) | ((uint32)f2bf(bb.y) << 16);
            o.w = f2bf(bb.z) | ((uint32)f2bf(bb.w) << 16);
            ((uint4*)xh)[id] = o;
        }
    } else if (b < nbConv + nbRp) {
        const int e = (b - nbConv) * 256 + threadIdx.x;
        if (e < n_edges) {
            const int r = row[e];
            const int rp = (e == 0) ? -1 : row[e - 1];
            for (int n = rp + 1; n <= r; ++n) row_ptr[n] = e;
            if (e == n_edges - 1)
                for (int n = r + 1; n <= n_nodes; ++n) row_ptr[n] = n_edges;
        }
    } else {
        const int id = (b - nbConv - nbRp) * 256 + threadIdx.x;   // 0..16383
        if (id < 16384) {
            const int n = id & 127, k = id >> 7;
            Wlt[n * 128 + k] = f2bf(Wl[k * 128 + n]);
            Wrt[n * 128 + k] = f2bf(Wr[k * 128 + n]);
        }
    }
}

// ---------------------------------------------------------------------------
// SpMM bf16. One wave per node; 4 edge-groups x 16 lanes; main loop unrolled
// x4 (16 gathers in flight per wave); 32-bit voffset addressing.
// ---------------------------------------------------------------------------
__global__ __launch_bounds__(256) void spmm_bf16_kernel(
    const unsigned short* __restrict__ xh,
    const int* __restrict__ row_ptr,
    const int* __restrict__ col,
    const float* __restrict__ val,
    unsigned short* __restrict__ outlh, int n_nodes) {
    const int wid = threadIdx.x >> 6;
    const int n = blockIdx.x * 4 + wid;
    if (n >= n_nodes) return;
    const int lane = threadIdx.x & 63;
    const int g = lane >> 4;
    const int q8 = (lane & 15) * 8;

    const int start = row_ptr[n];
    const int end = row_ptr[n + 1];

    float acc[8] = {0.f, 0.f, 0.f, 0.f, 0.f, 0.f, 0.f, 0.f};

    int i = start + g;
    // main: 4 edges per group per iteration -> 16 gathers in flight per wave
    for (; i + 12 < end; i += 16) {
        const int c0 = col[i];      const float v0 = val[i];
        const int c1 = col[i + 4];  const float v1 = val[i + 4];
        const int c2 = col[i + 8];  const float v2 = val[i + 8];
        const int c3 = col[i + 12]; const float v3 = val[i + 12];
        const uint4 r0 = *(const uint4*)&xh[c0 * D + q8];
        const uint4 r1 = *(const uint4*)&xh[c1 * D + q8];
        const uint4 r2 = *(const uint4*)&xh[c2 * D + q8];
        const uint4 r3 = *(const uint4*)&xh[c3 * D + q8];
        fma8(acc, r0, v0);
        fma8(acc, r1, v1);
        fma8(acc, r2, v2);
        fma8(acc, r3, v3);
    }
    // tail: 1 edge per group, 1-ahead prefetch
    int c = 0; float v = 0.f;
    if (i < end) { c = col[i]; v = val[i]; }
    while (i < end) {
        const int i2 = i + 4;
        int c2 = 0; float v2 = 0.f;
        if (i2 < end) { c2 = col[i2]; v2 = val[i2]; }
        const uint4 r = *(const uint4*)&xh[c * D + q8];
        fma8(acc, r, v);
        i = i2; c = c2; v = v2;
    }
#pragma unroll
    for (int j = 0; j < 8; ++j) {
        acc[j] += __shfl_xor(acc[j], 16, 64);
        acc[j] += __shfl_xor(acc[j], 32, 64);
    }
    if (g == 0) {
        uint4 o;
        o.x = f2bf(acc[0]) | ((uint32)f2bf(acc[1]) << 16);
        o.y = f2bf(acc[2]) | ((uint32)f2bf(acc[3]) << 16);
        o.z = f2bf(acc[4]) | ((uint32)f2bf(acc[5]) << 16);
        o.w = f2bf(acc[6]) | ((uint32)f2bf(acc[7]) << 16);
        *(uint4*)&outlh[n * D + q8] = o;
    }
}

// ---------------------------------------------------------------------------
// MFMA GEMM: out = [out_l_h | xh] @ [Wlt;Wrt]^T + b_l  (K=256 bf16 -> f32)
// 64x128 tile per block, 4 waves (2x2), wave tile 32x64; fragments direct
// from global.
// ---------------------------------------------------------------------------
__global__ __launch_bounds__(256) void gemm_mfma_kernel(
    const unsigned short* __restrict__ xh,
    const unsigned short* __restrict__ outlh,
    const unsigned short* __restrict__ Wlt,
    const unsigned short* __restrict__ Wrt,
    const float* __restrict__ b_l,
    float* __restrict__ out, int M) {
    const int tid = threadIdx.x;
    const int wid = tid >> 6, lane = tid & 63;
    const int wm = wid >> 1, wn = wid & 1;
    const int m0 = blockIdx.x * 64 + wm * 32;
    const int n0 = wn * 64;
    const int fr = lane & 15;
    const int kofs = (lane >> 4) * 8;

    f32x4 acc[2][4];
#pragma unroll
    for (int mr = 0; mr < 2; ++mr)
#pragma unroll
        for (int nr = 0; nr < 4; ++nr) acc[mr][nr] = (f32x4){0.f, 0.f, 0.f, 0.f};

#pragma unroll
    for (int s = 0; s < 8; ++s) {
        const unsigned short* Abase = (s < 4) ? outlh : xh;
        const unsigned short* Wbase = (s < 4) ? Wlt : Wrt;
        const int k0 = (s & 3) * 32;
        bf16x8 a[2], b[4];
#pragma unroll
        for (int mr = 0; mr < 2; ++mr)
            a[mr] = *(const bf16x8*)&Abase[(m0 + mr * 16 + fr) * D + k0 + kofs];
#pragma unroll
        for (int nr = 0; nr < 4; ++nr)
            b[nr] = *(const bf16x8*)&Wbase[(n0 + nr * 16 + fr) * D + k0 + kofs];
#pragma unroll
        for (int mr = 0; mr < 2; ++mr)
#pragma unroll
            for (int nr = 0; nr < 4; ++nr)
                acc[mr][nr] = __builtin_amdgcn_mfma_f32_16x16x32_bf16(
                    a[mr], b[nr], acc[mr][nr], 0, 0, 0);
    }

    const int r0 = (lane >> 4) * 4;
#pragma unroll
    for (int nr = 0; nr < 4; ++nr) {
        const int ncol = n0 + nr * 16 + fr;
        const float bias = b_l[ncol];
#pragma unroll
        for (int mr = 0; mr < 2; ++mr) {
#pragma unroll
            for (int j = 0; j < 4; ++j) {
                const int m = m0 + mr * 16 + r0 + j;
                if (m < M) out[m * D + ncol] = acc[mr][nr][j] + bias;
            }
        }
    }
}

// ===========================================================================
// Fallback f32 path if ws is too small for bf16 staging.
// ===========================================================================
__global__ void build_rowptr_kernel(const int* __restrict__ row,
                                    int* __restrict__ row_ptr,
                                    int n_nodes, int n_edges) {
    int e = blockIdx.x * blockDim.x + threadIdx.x;
    if (e >= n_edges) return;
    int r = row[e];
    int rp = (e == 0) ? -1 : row[e - 1];
    for (int n = rp + 1; n <= r; ++n) row_ptr[n] = e;
    if (e == n_edges - 1)
        for (int n = r + 1; n <= n_nodes; ++n) row_ptr[n] = n_edges;
}

__global__ __launch_bounds__(128) void spmm_kernel(
    const float* __restrict__ x, const int* __restrict__ row_ptr,
    const int* __restrict__ col, const float* __restrict__ val,
    float* __restrict__ out_l) {
    const int n = blockIdx.x;
    const int d = threadIdx.x;
    const int start = row_ptr[n];
    const int end = row_ptr[n + 1];
    float acc = 0.0f;
    for (int e = start; e < end; ++e)
        acc += val[e] * x[(size_t)col[e] * D + d];
    out_l[(size_t)n * D + d] = acc;
}

__global__ __launch_bounds__(256) void fused_gemm_kernel(
    const float* __restrict__ xin, const float* __restrict__ W_l,
    const float* __restrict__ b_l, const float* __restrict__ W_r,
    float* __restrict__ out, int M) {
    __shared__ float As[64][68];
    __shared__ float Ws[64][132];
    const int tid = threadIdx.x;
    const int tx = tid & 15;
    const int ty = tid >> 4;
    const int ty4 = ty * 4;
    const int m0 = blockIdx.x * 64;
    float acc[4][8];
#pragma unroll
    for (int i = 0; i < 4; ++i)
#pragma unroll
        for (int j = 0; j < 8; ++j) acc[i][j] = 0.0f;
    for (int kt = 0; kt < 4; ++kt) {
        const float* Asrc = (kt < 2) ? out : xin;
        const float* Wsrc = (kt < 2) ? W_l : W_r;
        const int koff = (kt & 1) * 64;
        __syncthreads();
#pragma unroll
        for (int r = 0; r < 4; ++r) {
            const int idx = tid + r * 256;
            const int m = idx >> 4;
            const int kq = idx & 15;
            float4 a = make_float4(0.f, 0.f, 0.f, 0.f);
            if (m0 + m < M)
                a = *(const float4*)&Asrc[(size_t)(m0 + m) * D + koff + kq * 4];
            *(float4*)&As[m][kq * 4] = a;
        }
#pragma unroll
        for (int r = 0; r < 8; ++r) {
            const int idx = tid + r * 256;
            const int k = idx >> 5;
            const int j4 = idx & 31;
            *(float4*)&Ws[k][j4 * 4] =
                *(const float4*)&Wsrc[(size_t)(koff + k) * D + j4 * 4];
        }
        __syncthreads();
#pragma unroll 4
        for (int k = 0; k < 64; ++k) {
            const float a0 = As[ty4 + 0][k], a1 = As[ty4 + 1][k];
            const float a2 = As[ty4 + 2][k], a3 = As[ty4 + 3][k];
            const float4 w0 = *(const float4*)&Ws[k][tx * 4];
            const float4 w1 = *(const float4*)&Ws[k][64 + tx * 4];
            acc[0][0] += a0 * w0.x; acc[0][1] += a0 * w0.y; acc[0][2] += a0 * w0.z; acc[0][3] += a0 * w0.w;
            acc[0][4] += a0 * w1.x; acc[0][5] += a0 * w1.y; acc[0][6] += a0 * w1.z; acc[0][7] += a0 * w1.w;
            acc[1][0] += a1 * w0.x; acc[1][1] += a1 * w0.y; acc[1][2] += a1 * w0.z; acc[1][3] += a1 * w0.w;
            acc[1][4] += a1 * w1.x; acc[1][5] += a1 * w1.y; acc[1][6] += a1 * w1.z; acc[1][7] += a1 * w1.w;
            acc[2][0] += a2 * w0.x; acc[2][1] += a2 * w0.y; acc[2][2] += a2 * w0.z; acc[2][3] += a2 * w0.w;
            acc[2][4] += a2 * w1.x; acc[2][5] += a2 * w1.y; acc[2][6] += a2 * w1.z; acc[2][7] += a2 * w1.w;
            acc[3][0] += a3 * w0.x; acc[3][1] += a3 * w0.y; acc[3][2] += a3 * w0.z; acc[3][3] += a3 * w0.w;
            acc[3][4] += a3 * w1.x; acc[3][5] += a3 * w1.y; acc[3][6] += a3 * w1.z; acc[3][7] += a3 * w1.w;
        }
    }
    const float4 bv0 = *(const float4*)&b_l[tx * 4];
    const float4 bv1 = *(const float4*)&b_l[64 + tx * 4];
#pragma unroll
    for (int i = 0; i < 4; ++i) {
        const int m = m0 + ty4 + i;
        if (m < M) {
            float4 o0, o1;
            o0.x = acc[i][0] + bv0.x; o0.y = acc[i][1] + bv0.y;
            o0.z = acc[i][2] + bv0.z; o0.w = acc[i][3] + bv0.w;
            o1.x = acc[i][4] + bv1.x; o1.y = acc[i][5] + bv1.y;
            o1.z = acc[i][6] + bv1.z; o1.w = acc[i][7] + bv1.w;
            *(float4*)&out[(size_t)m * D + tx * 4] = o0;
            *(float4*)&out[(size_t)m * D + 64 + tx * 4] = o1;
        }
    }
}

static inline size_t align256(size_t x) { return (x + 255) & ~(size_t)255; }

extern "C" void kernel_launch(void* const* d_in, const int* in_sizes, int n_in,
                              void* d_out, int out_size, void* d_ws, size_t ws_size,
                              hipStream_t stream) {
    const float* x   = (const float*)d_in[0];
    const int*   row = (const int*)d_in[1];
    const int*   col = (const int*)d_in[2];
    const float* val = (const float*)d_in[3];
    const float* W_l = (const float*)d_in[4];
    const float* b_l = (const float*)d_in[5];
    const float* W_r = (const float*)d_in[6];
    float* out = (float*)d_out;

    const int n_nodes = in_sizes[0] / D;
    const int n_edges = in_sizes[1];

    const size_t xh_bytes   = (size_t)n_nodes * D * 2;
    const size_t outl_bytes = (size_t)n_nodes * D * 2;
    const size_t wt_bytes   = (size_t)D * D * 2;
    const size_t rp_bytes   = (size_t)(n_nodes + 1) * 4;
    size_t off = 0;
    const size_t xh_off   = off; off += align256(xh_bytes);
    const size_t outl_off = off; off += align256(outl_bytes);
    const size_t wlt_off  = off; off += align256(wt_bytes);
    const size_t wrt_off  = off; off += align256(wt_bytes);
    const size_t rp_off   = off; off += align256(rp_bytes);
    const size_t needed   = off + 65536;

    if (ws_size >= needed) {
        unsigned short* xh    = (unsigned short*)((char*)d_ws + xh_off);
        unsigned short* outlh = (unsigned short*)((char*)d_ws + outl_off);
        unsigned short* Wlt   = (unsigned short*)((char*)d_ws + wlt_off);
        unsigned short* Wrt   = (unsigned short*)((char*)d_ws + wrt_off);
        int* row_ptr          = (int*)((char*)d_ws + rp_off);

        const int n8 = n_nodes * D / 8;
        const int nbConv = (n8 + 255) / 256;
        const int nbRp   = (n_edges + 255) / 256;
        const int nbW    = 64;
        prep_kernel<<<nbConv + nbRp + nbW, 256, 0, stream>>>(
            x, xh, n8, row, row_ptr, n_nodes, n_edges,
            W_l, W_r, Wlt, Wrt, nbConv, nbRp);
        spmm_bf16_kernel<<<(n_nodes + 3) / 4, 256, 0, stream>>>(
            xh, row_ptr, col, val, outlh, n_nodes);
        gemm_mfma_kernel<<<(n_nodes + 63) / 64, 256, 0, stream>>>(
            xh, outlh, Wlt, Wrt, b_l, out, n_nodes);
    } else {
        int* row_ptr = (int*)d_ws;
        build_rowptr_kernel<<<(n_edges + 255) / 256, 256, 0, stream>>>(
            row, row_ptr, n_nodes, n_edges);
        spmm_kernel<<<n_nodes, 128, 0, stream>>>(x, row_ptr, col, val, out);
        fused_gemm_kernel<<<(n_nodes + 63) / 64, 256, 0, stream>>>(
            x, W_l, b_l, W_r, out, n_nodes);
    }
}